// Round 9
// baseline (136.519 us; speedup 1.0000x reference)
//
#include <hip/hip_runtime.h>

// LGA2 fused: out = LGA(LGA(x,f),f), radius=2 (25 taps), fp32.
// x: [N=2, C=64, H=256, W=512], f: [N, 25, H, W], out like x.
//
// R9: 3-way tap split, 768 threads (12 waves).
//  - Allocator targets WG-granular occupancy: 12-wave blocks -> 2 WG/CU ->
//    6 waves/SIMD -> ~85 VGPR budget (R8 proved 8-wave blocks pin it at 64).
//  - Set A (tid<256) = filter rows 0-1 (taps 0-9, F0..F9 = 40 regs),
//    Set B = rows 2-3 (taps 10-19, same names), Set C = row 4 (taps 20-24)
//    + all combines + global stores. Max live filter regs 40 -> no spill.
//  - A,B write f4 partials to spA/spB; C adds own partial and finalizes.
//  - 4 lgkm-only barriers per channel; prefetch issued at loop top, landed
//    at iteration end (R7 timing; R8's mid-iteration landing regressed).
// Tile: temp 16x64, out 12x60, x region 20x68, stride 68 dwords.

typedef float f4 __attribute__((ext_vector_type(4)));
typedef float f2 __attribute__((ext_vector_type(2)));

#define OH 12
#define OW 60
#define STS 68
#define SXN (20 * STS)   // 1360 dwords per x buffer

#define TAPF(F,u0,u1,u2,u3) { a0=fmaf(F.x,u0,a0); a1=fmaf(F.y,u1,a1); \
                              a2=fmaf(F.z,u2,a2); a3=fmaf(F.w,u3,a3); }
#define ROW5(Fa,Fb,Fc,Fd,Fe,P) { const f4 xa=*(const f4*)(P); const f4 xb=*(const f4*)((P)+4); \
  TAPF(Fa,xa.x,xa.y,xa.z,xa.w) TAPF(Fb,xa.y,xa.z,xa.w,xb.x) TAPF(Fc,xa.z,xa.w,xb.x,xb.y) \
  TAPF(Fd,xa.w,xb.x,xb.y,xb.z) TAPF(Fe,xb.x,xb.y,xb.z,xb.w) }

// lgkm-only barrier: LDS ordered, global prefetch loads stay in flight
#define LBAR() { asm volatile("s_waitcnt lgkmcnt(0)" ::: "memory"); \
                 __builtin_amdgcn_s_barrier(); asm volatile("" ::: "memory"); }

__global__ __launch_bounds__(768)
void lga2_fused(const float* __restrict__ x, const float* __restrict__ f,
                float* __restrict__ out, int N, int C, int H, int W, int CPB) {
    const int tid = threadIdx.x;
    const int setid = tid >> 8;        // 0:A(rows 0-1) 1:B(rows 2-3) 2:C(row 4 + combine)
    const int t = tid & 255;
    const int r = t >> 4;              // temp-region row 0..15
    const int s = t & 15;              // quad-strip 0..15
    const int oh0 = blockIdx.y * OH;
    const int ow0 = blockIdx.x * OW;
    const int CG = C / CPB;
    const int n  = blockIdx.z / CG;
    const int c0 = (blockIdx.z % CG) * CPB;
    const int HW = H * W;

    __shared__ float sx[2][SXN];
    __shared__ float st[16 * STS];                    // temp: [2 g][64][2 g]/row
    __shared__ float spA[16 * STS], spB[16 * STS];    // partial exchange

    if (tid < 64) {                  // zero temp guard cols once
        int zr = tid >> 2, q = tid & 3;
        st[zr * STS + (q < 2 ? q : q + 64)] = 0.0f;
    }

    // ---- filter registers (named SSA f4 vars, 10 per set max) ----
    const int gh_f = oh0 - 2 + r;
    const int gwb  = ow0 - 2 + 4 * s;
    const bool rowok = (gh_f >= 0) && (gh_f < H);
    const bool p0ok = rowok && (gwb >= 0) && (gwb + 1 < W);
    const bool p1ok = rowok && (gwb + 3 < W);
    const float* fb = f + (size_t)(n * 25) * HW + (size_t)(rowok ? gh_f : 0) * W;

#define LDF(T) ({ f2 u_ = p0ok ? *(const f2*)(fb + (size_t)(T) * HW + gwb)     : f2{0.f, 0.f}; \
                  f2 v_ = p1ok ? *(const f2*)(fb + (size_t)(T) * HW + gwb + 2) : f2{0.f, 0.f}; \
                  f4{u_.x, u_.y, v_.x, v_.y}; })
#define PIN(F) asm volatile("" : "+v"(F));

    f4 F0,F1,F2,F3,F4,F5,F6,F7,F8,F9;
    if (setid == 0) {
        F0=LDF(0); F1=LDF(1); F2=LDF(2); F3=LDF(3); F4=LDF(4);
        F5=LDF(5); F6=LDF(6); F7=LDF(7); F8=LDF(8); F9=LDF(9);
    } else if (setid == 1) {
        F0=LDF(10); F1=LDF(11); F2=LDF(12); F3=LDF(13); F4=LDF(14);
        F5=LDF(15); F6=LDF(16); F7=LDF(17); F8=LDF(18); F9=LDF(19);
    } else {
        F0=LDF(20); F1=LDF(21); F2=LDF(22); F3=LDF(23); F4=LDF(24);
        F5=F6=F7=F8=F9=f4{0.f,0.f,0.f,0.f};
    }
    PIN(F0) PIN(F1) PIN(F2) PIN(F3) PIN(F4)
    PIN(F5) PIN(F6) PIN(F7) PIN(F8) PIN(F9)

    // ---- staging: 340 quads, one per thread (tid<340), linear ----
    const bool stg = (tid < 340);
    const int row0 = tid / 17, v0 = tid - row0 * 17;
    const int g0h = oh0 - 4 + row0, g0c = ow0 - 4 + 4 * v0;
    const bool ok0 = stg && (g0h >= 0) && (g0h < H) && (g0c >= 0) && (g0c + 3 < W);
    const int off0 = ok0 ? (g0h * W + g0c) : 0;
    const int l0 = 4 * tid;
    const f4 z4 = f4{0.f, 0.f, 0.f, 0.f};
    const float* xc = x + (size_t)(n * C + c0) * HW;

    if (stg) {                         // prologue: stage channel 0
        f4 p = ok0 ? *(const f4*)(xc + off0) : z4;
        *(f4*)&sx[0][l0] = p;
    }
    __syncthreads();

    const bool prow = (r >= 2) && (r <= 13) && (gh_f < H);

    int cur = 0;
    for (int cc = 0; cc < CPB; ++cc) {
        // issue prefetch for channel cc+1 (landed at iteration end)
        f4 nx = z4;
        const bool pf = (cc + 1 < CPB);
        if (pf && ok0) nx = *(const f4*)(xc + (size_t)(cc + 1) * HW + off0);

        // ---- pass 1 partials ----
        float c10 = 0.f, c11 = 0.f, c12 = 0.f, c13 = 0.f;   // C's own partial
        {
            const float* sxp = sx[cur];
            if (setid == 0) {
                float a0=0.f,a1=0.f,a2=0.f,a3=0.f;
                const float* P = sxp + r * STS + 4 * s;
                ROW5(F0,F1,F2,F3,F4, P)
                ROW5(F5,F6,F7,F8,F9, P + STS)
                *(f4*)&spA[r * STS + 4 * s] = f4{a0, a1, a2, a3};
            } else if (setid == 1) {
                float a0=0.f,a1=0.f,a2=0.f,a3=0.f;
                const float* P = sxp + (r + 2) * STS + 4 * s;
                ROW5(F0,F1,F2,F3,F4, P)
                ROW5(F5,F6,F7,F8,F9, P + STS)
                *(f4*)&spB[r * STS + 4 * s] = f4{a0, a1, a2, a3};
            } else {
                float a0=0.f,a1=0.f,a2=0.f,a3=0.f;
                const float* P = sxp + (r + 4) * STS + 4 * s;
                ROW5(F0,F1,F2,F3,F4, P)
                c10=a0; c11=a1; c12=a2; c13=a3;
            }
        }
        LBAR();   // bar1: spA/spB visible

        if (setid == 2) {              // combine -> temp
            f4 pa = *(const f4*)&spA[r * STS + 4 * s];
            f4 pb = *(const f4*)&spB[r * STS + 4 * s];
            *(f2*)&st[r * STS + 2 + 4 * s] = f2{pa.x + pb.x + c10, pa.y + pb.y + c11};
            *(f2*)&st[r * STS + 4 + 4 * s] = f2{pa.z + pb.z + c12, pa.w + pb.w + c13};
        }
        LBAR();   // bar2: temp visible

        // ---- pass 2 partials ----
        c10 = c11 = c12 = c13 = 0.f;
        if (prow) {
            if (setid == 0) {
                float a0=0.f,a1=0.f,a2=0.f,a3=0.f;
                const float* Q = st + (r - 2) * STS + 4 * s;
                ROW5(F0,F1,F2,F3,F4, Q)
                ROW5(F5,F6,F7,F8,F9, Q + STS)
                *(f4*)&spA[r * STS + 4 * s] = f4{a0, a1, a2, a3};
            } else if (setid == 1) {
                float a0=0.f,a1=0.f,a2=0.f,a3=0.f;
                const float* Q = st + r * STS + 4 * s;
                ROW5(F0,F1,F2,F3,F4, Q)
                ROW5(F5,F6,F7,F8,F9, Q + STS)
                *(f4*)&spB[r * STS + 4 * s] = f4{a0, a1, a2, a3};
            } else {
                float a0=0.f,a1=0.f,a2=0.f,a3=0.f;
                const float* Q = st + (r + 2) * STS + 4 * s;
                ROW5(F0,F1,F2,F3,F4, Q)
                c10=a0; c11=a1; c12=a2; c13=a3;
            }
        }
        LBAR();   // bar3: spA/spB (p2) visible

        if (setid == 2 && prow) {      // combine -> global
            f4 pa = *(const f4*)&spA[r * STS + 4 * s];
            f4 pb = *(const f4*)&spB[r * STS + 4 * s];
            float o0 = pa.x + pb.x + c10, o1 = pa.y + pb.y + c11;
            float o2 = pa.z + pb.z + c12, o3 = pa.w + pb.w + c13;
            float* op = out + ((size_t)(n * C + c0 + cc) * H + gh_f) * W + gwb;
            if (s >= 1 && gwb + 1 < W)  *(f2*)op       = f2{o0, o1};
            if (s <= 14 && gwb + 3 < W) *(f2*)(op + 2) = f2{o2, o3};
        }

        // land prefetch into the other buffer (no reads of it in flight)
        if (pf && stg) *(f4*)&sx[cur ^ 1][l0] = nx;
        LBAR();   // bar4: next channel's x visible
        cur ^= 1;
    }
}

extern "C" void kernel_launch(void* const* d_in, const int* in_sizes, int n_in,
                              void* d_out, int out_size, void* d_ws, size_t ws_size,
                              hipStream_t stream) {
    const float* x = (const float*)d_in[0];
    const float* f = (const float*)d_in[1];
    float* out = (float*)d_out;

    const int N = 2, C = 64, H = 256, W = 512;
    const int CPB = 32;
    const int CG = C / CPB;                    // 2

    dim3 grid((W + OW - 1) / OW,               // 9
              (H + OH - 1) / OH,               // 22
              N * CG);                         // 4  -> 792 blocks of 768 thr
    lga2_fused<<<grid, 768, 0, stream>>>(x, f, out, N, C, H, W, CPB);
}

// Round 13
// 79.428 us; speedup vs baseline: 1.7188x; 1.7188x over previous
//
#include <hip/hip_runtime.h>
#include <hip/hip_fp16.h>

// LGA2 fused: out = LGA(LGA(x,f),f), radius=2 (25 taps), fp32 in/out.
// x: [N=2, C=64, H=256, W=512], f: [N, 25, H, W], out like x.
//
// R11 = R10 with the cvt_pkrtz return-type fix (__fp16 vector, not _Float16).
//
// R10: fp16-packed operands + v_fma_mix_f32 (f32 accumulate).
//  - Filter state halves to 50 VGPRs (25 taps x 2 half2) -> full 25 taps per
//    thread at 256-thr blocks, where the allocator's observed ceiling (~92)
//    fits. No tap split, no partial exchange, 2 lgkm barriers/channel.
//  - x and temp staged in LDS as f16 (cvt_pkrtz at staging): window reads are
//    2x ds_read_b64 per row; op_sel picks the shifted half statically.
//  - f32 accumulation via v_fma_mix -> only input-quantization error (~0.3
//    absmax vs 2.94 threshold).
//  - CPB=16 -> 1584 blocks (6.2/CU) for latency hiding; halo re-reads are
//    L2/L3-resident.
// Tile: temp 16x64, out 12x60, x region 20x68. Row stride 80 halves (=40
// uints, bank stride 8 -> even bank spread for 4-rows-per-wave b64 reads).

typedef __fp16 h2v __attribute__((ext_vector_type(2)));

#define OH 12
#define OW 60
#define USH 40            // uints per LDS row (80 halves)

__device__ __forceinline__ unsigned pkh(float a, float b) {
    union { h2v h; unsigned u; } c;
    c.h = __builtin_amdgcn_cvt_pkrtz(a, b);
    return c.u;
}

// d += f16(fv half sf) * f16(xv half sx)  with f32 accumulate
#define M(ac, fv, xv, sf, sx) \
    asm("v_fma_mix_f32 %0, %1, %2, %0 op_sel:[" #sf "," #sx ",0] op_sel_hi:[1,1,0]" \
        : "+v"(ac) : "v"(fv), "v"(xv));

// One filter row (taps T..T+4) against window halves w0..w3 (cols h=0..7,
// h = k + j for output col k, tap col j). acc names a0..a3 fixed.
#define ROWM(T, w0, w1, w2, w3) \
  M(a0,frA[T+0],w0,0,0) M(a1,frA[T+0],w0,1,1) M(a2,frB[T+0],w1,0,0) M(a3,frB[T+0],w1,1,1) \
  M(a0,frA[T+1],w0,0,1) M(a1,frA[T+1],w1,1,0) M(a2,frB[T+1],w1,0,1) M(a3,frB[T+1],w2,1,0) \
  M(a0,frA[T+2],w1,0,0) M(a1,frA[T+2],w1,1,1) M(a2,frB[T+2],w2,0,0) M(a3,frB[T+2],w2,1,1) \
  M(a0,frA[T+3],w1,0,1) M(a1,frA[T+3],w2,1,0) M(a2,frB[T+3],w2,0,1) M(a3,frB[T+3],w3,1,0) \
  M(a0,frA[T+4],w2,0,0) M(a1,frA[T+4],w2,1,1) M(a2,frB[T+4],w3,0,0) M(a3,frB[T+4],w3,1,1)

// lgkm-only barrier: LDS ordered, global prefetch loads stay in flight
#define LBAR() { asm volatile("s_waitcnt lgkmcnt(0)" ::: "memory"); \
                 __builtin_amdgcn_s_barrier(); asm volatile("" ::: "memory"); }

__global__ __launch_bounds__(256)
void lga2_fused(const float* __restrict__ x, const float* __restrict__ f,
                float* __restrict__ out, int N, int C, int H, int W, int CPB) {
    const int tid = threadIdx.x;
    const int r = tid >> 4;            // temp-region row 0..15
    const int s = tid & 15;            // quad-strip 0..15 (temp cols 4s..4s+3)
    const int oh0 = blockIdx.y * OH;
    const int ow0 = blockIdx.x * OW;
    const int CG = C / CPB;
    const int n  = blockIdx.z / CG;
    const int c0 = (blockIdx.z % CG) * CPB;
    const int HW = H * W;

    __shared__ unsigned sxU[2][20 * USH];   // x as f16: 20 rows x 80 halves
    __shared__ unsigned stU[16 * USH];      // temp as f16: [2g][64][2g] halves

    // zero temp guard halves (storage halves 0,1 and 66,67 per row) once
    if (tid < 32) {
        int row = tid & 15;
        stU[row * USH + ((tid & 16) ? 33 : 0)] = 0u;
    }

    // ---- filter registers: 25 taps x 2 packed half2 (cols gwb..gwb+3) ----
    const int gh_f = oh0 - 2 + r;          // this thread's temp/out row
    const int gwb  = ow0 - 2 + 4 * s;      // first col of the quad (even)
    const bool rowok = (gh_f >= 0) && (gh_f < H);
    const bool p0ok = rowok && (gwb >= 0) && (gwb + 1 < W);
    const bool p1ok = rowok && (gwb + 3 < W);
    const float* fb = f + (size_t)(n * 25) * HW + (size_t)(rowok ? gh_f : 0) * W;

    unsigned frA[25], frB[25];
    #pragma unroll
    for (int t = 0; t < 25; ++t) {
        float2 v01 = p0ok ? *(const float2*)(fb + (size_t)t * HW + gwb)
                          : make_float2(0.f, 0.f);
        float2 v23 = p1ok ? *(const float2*)(fb + (size_t)t * HW + gwb + 2)
                          : make_float2(0.f, 0.f);
        frA[t] = pkh(v01.x, v01.y);
        frB[t] = pkh(v23.x, v23.y);
        if ((t % 5) == 4) __builtin_amdgcn_sched_barrier(0);  // cap load burst
    }
    #pragma unroll
    for (int t = 0; t < 25; ++t)
        asm volatile("" : "+v"(frA[t]), "+v"(frB[t]));   // pin packed filters

    // ---- staging: 340 quads (20 rows x 17), thread handles tid and tid+256 ----
    const int i1 = tid + 256;
    const bool has1 = (tid < 340 - 256);
    const int row0 = tid / 17, v0 = tid - row0 * 17;
    const int row1 = i1 / 17,  v1 = i1 - row1 * 17;
    const int g0h = oh0 - 4 + row0, g0c = ow0 - 4 + 4 * v0;
    const int g1h = oh0 - 4 + row1, g1c = ow0 - 4 + 4 * v1;
    const bool ok0 = (g0h >= 0) && (g0h < H) && (g0c >= 0) && (g0c + 3 < W);
    const bool ok1 = has1 && (g1h >= 0) && (g1h < H) && (g1c >= 0) && (g1c + 3 < W);
    const int off0 = ok0 ? (g0h * W + g0c) : 0;
    const int off1 = ok1 ? (g1h * W + g1c) : 0;
    const int l0u = row0 * USH + 2 * v0;
    const int l1u = row1 * USH + 2 * v1;

    const float4 z4 = make_float4(0.f, 0.f, 0.f, 0.f);
    const float* xc = x + (size_t)(n * C + c0) * HW;

    {   // prologue: stage channel 0 into buffer 0 (zeros for OOB quads)
        float4 p = ok0 ? *(const float4*)(xc + off0) : z4;
        *(uint2*)&sxU[0][l0u] = make_uint2(pkh(p.x, p.y), pkh(p.z, p.w));
        if (has1) {
            float4 q = ok1 ? *(const float4*)(xc + off1) : z4;
            *(uint2*)&sxU[0][l1u] = make_uint2(pkh(q.x, q.y), pkh(q.z, q.w));
        }
    }
    __syncthreads();

    const bool prow = (r >= 2) && (r <= 13) && (gh_f < H);
    const int rc = (r < 2) ? 2 : ((r > 13) ? 13 : r);   // clamp for p2 reads
    float* op = out + ((size_t)(n * C + c0) * H + gh_f) * W + gwb;

    int cur = 0;
    for (int cc = 0; cc < CPB; ++cc) {
        // issue prefetch for channel cc+1 (landed at iteration end)
        float4 nx0 = z4, nx1 = z4;
        const bool pf = (cc + 1 < CPB);
        if (pf) {
            const float* xn = xc + (size_t)(cc + 1) * HW;
            if (ok0) nx0 = *(const float4*)(xn + off0);
            if (ok1) nx1 = *(const float4*)(xn + off1);
        }

        // ---- pass 1: temp(r, 4s..4s+3); x window halves 4s..4s+7 of rows r..r+4
        float a0 = 0.f, a1 = 0.f, a2 = 0.f, a3 = 0.f;
        {
            const unsigned* sxp = sxU[cur];
            #pragma unroll
            for (int i = 0; i < 5; ++i) {
                const int b = (r + i) * USH + 2 * s;
                uint2 lo = *(const uint2*)&sxp[b];
                uint2 hi = *(const uint2*)&sxp[b + 2];
                ROWM(5 * i, lo.x, lo.y, hi.x, hi.y)
            }
        }
        stU[r * USH + 1 + 2 * s] = pkh(a0, a1);   // storage halves 2+4s..
        stU[r * USH + 2 + 2 * s] = pkh(a2, a3);
        LBAR();   // temp visible

        // ---- pass 2: same window pattern on temp (storage halves 4s..4s+7)
        a0 = 0.f; a1 = 0.f; a2 = 0.f; a3 = 0.f;
        #pragma unroll
        for (int i = 0; i < 5; ++i) {
            const int b = (rc - 2 + i) * USH + 2 * s;
            uint2 lo = *(const uint2*)&stU[b];
            uint2 hi = *(const uint2*)&stU[b + 2];
            ROWM(5 * i, lo.x, lo.y, hi.x, hi.y)
        }
        if (prow) {
            if (s >= 1 && gwb + 1 < W)  *(float2*)op       = make_float2(a0, a1);
            if (s <= 14 && gwb + 3 < W) *(float2*)(op + 2) = make_float2(a2, a3);
        }

        // ---- land prefetch into the other buffer (zeros for OOB stay zero) ----
        if (pf) {
            *(uint2*)&sxU[cur ^ 1][l0u] = make_uint2(pkh(nx0.x, nx0.y), pkh(nx0.z, nx0.w));
            if (has1)
                *(uint2*)&sxU[cur ^ 1][l1u] = make_uint2(pkh(nx1.x, nx1.y), pkh(nx1.z, nx1.w));
        }
        LBAR();   // next x visible; temp reads drained before next p1 write
        cur ^= 1;
        op += HW;
    }
}

extern "C" void kernel_launch(void* const* d_in, const int* in_sizes, int n_in,
                              void* d_out, int out_size, void* d_ws, size_t ws_size,
                              hipStream_t stream) {
    const float* x = (const float*)d_in[0];
    const float* f = (const float*)d_in[1];
    float* out = (float*)d_out;

    const int N = 2, C = 64, H = 256, W = 512;
    const int CPB = 16;                        // 4 channel groups
    const int CG = C / CPB;

    dim3 grid((W + OW - 1) / OW,               // 9
              (H + OH - 1) / OH,               // 22
              N * CG);                         // 8  -> 1584 blocks of 256 thr
    lga2_fused<<<grid, 256, 0, stream>>>(x, f, out, N, C, H, W, CPB);
}